// Round 9
// baseline (286.609 us; speedup 1.0000x reference)
//
#include <hip/hip_runtime.h>

// Fused capsule conv + dynamic routing: 2 pixels/block, MFMA, XCD-ownership.
// x:      [8, 32, 8, 32, 32] f32   (bs, ci, ni, hi, wi)
// conv_w: [256, 8, 3, 3]     f32   (co*no, ni, kh, kw)
// bias:   [32, 8, 1, 1]      f32
// out:    [8, 32, 8, 32, 32] f32   (bs, co, no, ho, wo)
//
// R7 was chain-serialized (VALU 46% + DS ~60us additive; occupancy and HBM
// both proven non-binding). This round: block = pixel pair (hw, hw+1) as one
// M=64 GEMM (acc[4][4], B-frags shared), px-unrolled routing = 2 independent
// chains/thread (ILP-2). K repacked [hi72|lo72|0]=160 with W'=[w|w|0]:
// 5 k-steps (-17% MFMA). Barriers: 6 per 2 pixels. Staging writes packed
// to ds_write_b32. Output float2. LDS 21.5KB, routing aliased into dead A.

typedef __attribute__((ext_vector_type(8))) short short8;
typedef __attribute__((ext_vector_type(4))) float f32x4;

#define LSTR 168   // A row stride in ushorts (336 B, 16B-mult, bank-spread)
#define KP   160   // packed K per col: [hi 72][lo 72][zero 16]
#define RSTR 36    // routeT row stride (f32)

__device__ __forceinline__ float bf2f(ushort h) {
    return __uint_as_float(((unsigned)h) << 16);
}
__device__ __forceinline__ ushort f2bf_rne(float f) {
    unsigned u = __float_as_uint(f);
    return (ushort)((u + 0x7fffu + ((u >> 16) & 1u)) >> 16);
}

__global__ void prep_w(const float* __restrict__ cw, ushort* __restrict__ wp) {
    int e = blockIdx.x * 256 + threadIdx.x;   // [col=256][k=160]
    int col = e / KP, k = e - col * KP;
    float v = 0.0f;
    if (k < 144) v = cw[col * 72 + (k < 72 ? k : k - 72)];
    wp[e] = f2bf_rne(v);
}

__global__ __launch_bounds__(256, 6)
void caps_mfma2(const float* __restrict__ x,
                const ushort* __restrict__ wp,
                const float* __restrict__ bias,
                float* __restrict__ out)
{
    // A [64 rows][LSTR] = 21,504 B; dead after GEMM. Aliased per pixel:
    //   logits0 @ f[0..1056), routeT0 @ f[1056..2208),
    //   logits1 @ f[2208..3264), routeT1 @ f[3264..4416)   (17,664 B)
    __shared__ ushort A[64 * LSTR];
    float* fA = reinterpret_cast<float*>(A);

    const int t    = threadIdx.x;
    const int braw = blockIdx.x;                 // grid = 4096
    // XCD-ownership swizzle (bijective, 4096 = 8*512): XCD k owns batch k.
    const int bid = ((braw & 7) << 9) | (braw >> 3);
    const int b   = bid >> 9;
    const int q   = bid & 511;
    const int hw0 = q << 1;                      // even; pair = (hw0, hw0+1)
    const int h   = hw0 >> 5;
    const int w0  = hw0 & 31;                    // even, <= 30

    // ---- stage A rows: thread t <-> (row = t>>2 = px*32+ci, ni in {2qn,2qn+1})
    {
        const int row = t >> 2, qn = t & 3;
        const int px = row >> 5, ci = row & 31;
        const int wpx = w0 + px;
        const float* xb0 = x + (((size_t)((b * 32 + ci) * 8 + qn * 2)) << 10);
        const float* xb1 = xb0 + 1024;
        ushort hbuf[18], lbuf[18];
        #pragma unroll
        for (int kh = 0; kh < 3; ++kh) {
            int hy = h + kh - 1;
            bool vh = (unsigned)hy < 32u;
            int base = hy << 5;
            #pragma unroll
            for (int c = 0; c < 3; ++c) {
                int wx = wpx + c - 1;
                bool ok = vh && ((unsigned)wx < 32u);
                float f0 = ok ? xb0[base + wx] : 0.0f;
                float f1 = ok ? xb1[base + wx] : 0.0f;
                ushort h0 = (ushort)(__float_as_uint(f0) >> 16);   // trunc split
                ushort h1 = (ushort)(__float_as_uint(f1) >> 16);
                float lo0 = f0 - bf2f(h0);
                float lo1 = f1 - bf2f(h1);
                int k0 = kh * 3 + c, k1 = 9 + kh * 3 + c;
                hbuf[k0] = h0; lbuf[k0] = (ushort)(__float_as_uint(lo0) >> 16);
                hbuf[k1] = h1; lbuf[k1] = (ushort)(__float_as_uint(lo1) >> 16);
            }
        }
        // packed writes: hi at shorts [row*LSTR + qn*18, +18), lo at +72
        uint* Au = reinterpret_cast<uint*>(A);
        int hbase = (row * LSTR + qn * 18) >> 1;   // both even -> exact
        int lbase = hbase + 36;
        #pragma unroll
        for (int i = 0; i < 9; ++i) {
            Au[hbase + i] = (unsigned)hbuf[2 * i] | ((unsigned)hbuf[2 * i + 1] << 16);
            Au[lbase + i] = (unsigned)lbuf[2 * i] | ((unsigned)lbuf[2 * i + 1] << 16);
        }
        // zero K-pad shorts 144..159 (8 uints/row, 4 threads -> 2 each)
        int pbase = (row * LSTR + 144) >> 1;
        Au[pbase + qn * 2]     = 0u;
        Au[pbase + qn * 2 + 1] = 0u;
    }
    __syncthreads();

    const int lane = t & 63, wv = t >> 6;
    const int lc = lane & 15, grp = lane >> 4;
    const int no = lane & 7;
    const int par = (lane >> 3) & 1;

    // ---- GEMM: D[64 rows][256 cols], rows = px*32+ci. 5 k-steps of 32.
    f32x4 acc[4][4];
    #pragma unroll
    for (int mt = 0; mt < 4; ++mt)
        #pragma unroll
        for (int j = 0; j < 4; ++j) acc[mt][j] = (f32x4){0.f, 0.f, 0.f, 0.f};

    for (int ks = 0; ks < 5; ++ks) {
        short8 bq[4];
        #pragma unroll
        for (int j = 0; j < 4; ++j) {
            int col = wv * 64 + j * 16 + lc;
            bq[j] = *reinterpret_cast<const short8*>(wp + col * KP + ks * 32 + grp * 8);
        }
        short8 af[4];
        #pragma unroll
        for (int mt = 0; mt < 4; ++mt)
            af[mt] = *reinterpret_cast<const short8*>(A + (mt * 16 + lc) * LSTR + ks * 32 + grp * 8);
        #pragma unroll
        for (int mt = 0; mt < 4; ++mt)
            #pragma unroll
            for (int j = 0; j < 4; ++j)
                acc[mt][j] = __builtin_amdgcn_mfma_f32_16x16x32_bf16(af[mt], bq[j], acc[mt][j], 0, 0, 0);
    }
    __syncthreads();   // A dead; logits/routeT alias its LDS from here

    float bj[4];
    #pragma unroll
    for (int j = 0; j < 4; ++j) bj[j] = bias[wv * 64 + j * 16 + lc];

    const int ci_s = t >> 3, j_s = t & 7;
    float act_[2][4];

    // ================= iteration 0: route = 1/32 exactly =================
    #pragma unroll
    for (int px = 0; px < 2; ++px) {
        #pragma unroll
        for (int j = 0; j < 4; ++j) {
            const f32x4 a0 = acc[px * 2][j], a1 = acc[px * 2 + 1][j];
            float p = a0[0] + a0[1] + a0[2] + a0[3] + a1[0] + a1[1] + a1[2] + a1[3];
            p += __shfl_xor(p, 16);
            p += __shfl_xor(p, 32);             // sum over 32 ci
            p = p * 0.03125f + bj[j];
            float s2 = p * p;
            s2 += __shfl_xor(s2, 1);
            s2 += __shfl_xor(s2, 2);
            s2 += __shfl_xor(s2, 4);            // sum over no
            act_[px][j] = p * sqrtf(s2) / (1.0f + s2);
        }
    }
    // distances -> logits (pure write of all 1024 (ci,co) per pixel)
    #pragma unroll
    for (int px = 0; px < 2; ++px) {
        float* lg = px ? (fA + 2208) : fA;
        #pragma unroll
        for (int j = 0; j < 4; ++j) {
            float a = act_[px][j];
            float d[8];
            #pragma unroll
            for (int r = 0; r < 4; ++r) { d[r] = acc[px * 2][j][r] * a; d[4 + r] = acc[px * 2 + 1][j][r] * a; }
            const bool b4 = (no & 4) != 0, b2 = (no & 2) != 0, b1 = (no & 1) != 0;
            float e[4];
            #pragma unroll
            for (int k = 0; k < 4; ++k) {
                float keep = b4 ? d[k + 4] : d[k];
                float send = b4 ? d[k] : d[k + 4];
                e[k] = keep + __shfl_xor(send, 4);
            }
            float f2_[2];
            #pragma unroll
            for (int k = 0; k < 2; ++k) {
                float keep = b2 ? e[k + 2] : e[k];
                float send = b2 ? e[k] : e[k + 2];
                f2_[k] = keep + __shfl_xor(send, 2);
            }
            float keep = b1 ? f2_[1] : f2_[0];
            float send = b1 ? f2_[0] : f2_[1];
            float r = keep + __shfl_xor(send, 1);
            int ci_w = ((no >> 2) << 4) + (grp << 2) + (no & 3);
            int co   = (wv << 3) + 2 * j + par;
            lg[ci_w * 33 + co] = r;
        }
    }
    __syncthreads();

    // ================= iterations 1 and 2 =================
    for (int it = 1; it <= 2; ++it) {
        // (a) softmax over co per pixel; store transposed routeT[co][ci]
        #pragma unroll
        for (int px = 0; px < 2; ++px) {
            float* lg = px ? (fA + 2208) : fA;
            float* rt = px ? (fA + 3264) : (fA + 1056);
            float l0 = lg[ci_s * 33 + j_s];
            float l1 = lg[ci_s * 33 + j_s + 8];
            float l2 = lg[ci_s * 33 + j_s + 16];
            float l3 = lg[ci_s * 33 + j_s + 24];
            float mx = fmaxf(fmaxf(l0, l1), fmaxf(l2, l3));
            mx = fmaxf(mx, __shfl_xor(mx, 1));
            mx = fmaxf(mx, __shfl_xor(mx, 2));
            mx = fmaxf(mx, __shfl_xor(mx, 4));
            float e0 = __expf(l0 - mx), e1 = __expf(l1 - mx);
            float e2 = __expf(l2 - mx), e3 = __expf(l3 - mx);
            float s = e0 + e1 + e2 + e3;
            s += __shfl_xor(s, 1); s += __shfl_xor(s, 2); s += __shfl_xor(s, 4);
            float inv = 1.0f / s;
            rt[(j_s)      * RSTR + ci_s] = e0 * inv;
            rt[(j_s + 8)  * RSTR + ci_s] = e1 * inv;
            rt[(j_s + 16) * RSTR + ci_s] = e2 * inv;
            rt[(j_s + 24) * RSTR + ci_s] = e3 * inv;
        }
        __syncthreads();

        // (b) preactivate (ci-reduce xor16/32) + squash (no-reduce xor1/2/4)
        #pragma unroll
        for (int px = 0; px < 2; ++px) {
            float* rt = px ? (fA + 3264) : (fA + 1056);
            #pragma unroll
            for (int j = 0; j < 4; ++j) {
                int co = (wv << 3) + 2 * j + par;
                f32x4 r0 = *reinterpret_cast<const f32x4*>(rt + co * RSTR + grp * 4);
                f32x4 r1 = *reinterpret_cast<const f32x4*>(rt + co * RSTR + 16 + grp * 4);
                float p = 0.0f;
                #pragma unroll
                for (int r = 0; r < 4; ++r) p = fmaf(r0[r], acc[px * 2][j][r], p);
                #pragma unroll
                for (int r = 0; r < 4; ++r) p = fmaf(r1[r], acc[px * 2 + 1][j][r], p);
                p += __shfl_xor(p, 16);
                p += __shfl_xor(p, 32);
                p += bj[j];
                float s2 = p * p;
                s2 += __shfl_xor(s2, 1);
                s2 += __shfl_xor(s2, 2);
                s2 += __shfl_xor(s2, 4);
                act_[px][j] = p * sqrtf(s2) / (1.0f + s2);
            }
        }
        if (it == 2) break;

        // (c) distances += (butterfly), accumulate into logits
        #pragma unroll
        for (int px = 0; px < 2; ++px) {
            float* lg = px ? (fA + 2208) : fA;
            #pragma unroll
            for (int j = 0; j < 4; ++j) {
                float a = act_[px][j];
                float d[8];
                #pragma unroll
                for (int r = 0; r < 4; ++r) { d[r] = acc[px * 2][j][r] * a; d[4 + r] = acc[px * 2 + 1][j][r] * a; }
                const bool b4 = (no & 4) != 0, b2 = (no & 2) != 0, b1 = (no & 1) != 0;
                float e[4];
                #pragma unroll
                for (int k = 0; k < 4; ++k) {
                    float keep = b4 ? d[k + 4] : d[k];
                    float send = b4 ? d[k] : d[k + 4];
                    e[k] = keep + __shfl_xor(send, 4);
                }
                float f2_[2];
                #pragma unroll
                for (int k = 0; k < 2; ++k) {
                    float keep = b2 ? e[k + 2] : e[k];
                    float send = b2 ? e[k] : e[k + 2];
                    f2_[k] = keep + __shfl_xor(send, 2);
                }
                float keep = b1 ? f2_[1] : f2_[0];
                float send = b1 ? f2_[0] : f2_[1];
                float r = keep + __shfl_xor(send, 1);
                int ci_w = ((no >> 2) << 4) + (grp << 2) + (no & 3);
                int co   = (wv << 3) + 2 * j + par;
                lg[ci_w * 33 + co] += r;
            }
        }
        __syncthreads();
    }

    // ---- output: grp 0 writes the wave's 64 cols, both pixels as float2
    if (grp == 0) {
        #pragma unroll
        for (int j = 0; j < 4; ++j) {
            int col = wv * 64 + j * 16 + lc;
            float2 v; v.x = act_[0][j]; v.y = act_[1][j];
            *reinterpret_cast<float2*>(out + ((((size_t)b << 8) + col) << 10) + hw0) = v;
        }
    }
}

extern "C" void kernel_launch(void* const* d_in, const int* in_sizes, int n_in,
                              void* d_out, int out_size, void* d_ws, size_t ws_size,
                              hipStream_t stream) {
    const float* x    = (const float*)d_in[0];
    const float* cw   = (const float*)d_in[1];
    const float* bias = (const float*)d_in[2];
    float* out = (float*)d_out;
    ushort* wp = (ushort*)d_ws;           // 256*160*2 = 81,920 B
    (void)in_sizes; (void)n_in; (void)out_size; (void)ws_size;
    prep_w<<<160, 256, 0, stream>>>(cw, wp);
    caps_mfma2<<<4096, 256, 0, stream>>>(x, wp, bias, out);
}

// Round 10
// 108.275 us; speedup vs baseline: 2.6470x; 2.6470x over previous
//
#include <hip/hip_runtime.h>

// Fused capsule conv + dynamic routing: 2 pixels/block, MFMA, XCD-ownership.
// x:      [8, 32, 8, 32, 32] f32   (bs, ci, ni, hi, wi)
// conv_w: [256, 8, 3, 3]     f32   (co*no, ni, kh, kw)
// bias:   [32, 8, 1, 1]      f32
// out:    [8, 32, 8, 32, 32] f32   (bs, co, no, ho, wo)
//
// R8 retry with the spill fixed: launch_bounds(256,4) gives a 128-VGPR cap
// (R8's (256,6) capped below the ~110-reg demand -> acc spilled to scratch
// -> 1 GB of HBM scratch traffic, 286us). A-frags loaded per-mt to keep
// peak pressure ~90 regs. Structure: block = pixel pair (hw, hw+1), M=64
// GEMM acc[4][4], B-frags shared across pixels, K packed [hi72|lo72|0]=160
// (5 k-steps), px-unrolled routing (2 independent chains/thread), barriers
// halved per pixel, float2 output stores.

typedef __attribute__((ext_vector_type(8))) short short8;
typedef __attribute__((ext_vector_type(4))) float f32x4;

#define LSTR 168   // A row stride in ushorts (336 B)
#define KP   160   // packed K per col: [hi 72][lo 72][zero 16]
#define RSTR 36    // routeT row stride (f32)

__device__ __forceinline__ float bf2f(ushort h) {
    return __uint_as_float(((unsigned)h) << 16);
}
__device__ __forceinline__ ushort f2bf_rne(float f) {
    unsigned u = __float_as_uint(f);
    return (ushort)((u + 0x7fffu + ((u >> 16) & 1u)) >> 16);
}

__global__ void prep_w(const float* __restrict__ cw, ushort* __restrict__ wp) {
    int e = blockIdx.x * 256 + threadIdx.x;   // [col=256][k=160]
    int col = e / KP, k = e - col * KP;
    float v = 0.0f;
    if (k < 144) v = cw[col * 72 + (k < 72 ? k : k - 72)];
    wp[e] = f2bf_rne(v);
}

__global__ __launch_bounds__(256, 4)
void caps_mfma2(const float* __restrict__ x,
                const ushort* __restrict__ wp,
                const float* __restrict__ bias,
                float* __restrict__ out)
{
    // A [64 rows][LSTR] = 21,504 B; dead after GEMM. Aliased per pixel:
    //   logits0 @ f[0..1056), routeT0 @ f[1056..2208),
    //   logits1 @ f[2208..3264), routeT1 @ f[3264..4416)   (17,664 B)
    __shared__ ushort A[64 * LSTR];
    float* fA = reinterpret_cast<float*>(A);

    const int t    = threadIdx.x;
    const int braw = blockIdx.x;                 // grid = 4096
    // XCD-ownership swizzle (bijective, 4096 = 8*512): XCD k owns batch k.
    const int bid = ((braw & 7) << 9) | (braw >> 3);
    const int b   = bid >> 9;
    const int q   = bid & 511;
    const int hw0 = q << 1;                      // even; pair = (hw0, hw0+1)
    const int h   = hw0 >> 5;
    const int w0  = hw0 & 31;                    // even, <= 30

    // ---- stage A rows: thread t <-> (row = t>>2 = px*32+ci, ni in {2qn,2qn+1})
    {
        const int row = t >> 2, qn = t & 3;
        const int px = row >> 5, ci = row & 31;
        const int wpx = w0 + px;
        const float* xb0 = x + (((size_t)((b * 32 + ci) * 8 + qn * 2)) << 10);
        const float* xb1 = xb0 + 1024;
        ushort hbuf[18], lbuf[18];
        #pragma unroll
        for (int kh = 0; kh < 3; ++kh) {
            int hy = h + kh - 1;
            bool vh = (unsigned)hy < 32u;
            int base = hy << 5;
            #pragma unroll
            for (int c = 0; c < 3; ++c) {
                int wx = wpx + c - 1;
                bool ok = vh && ((unsigned)wx < 32u);
                float f0 = ok ? xb0[base + wx] : 0.0f;
                float f1 = ok ? xb1[base + wx] : 0.0f;
                ushort h0 = (ushort)(__float_as_uint(f0) >> 16);   // trunc split
                ushort h1 = (ushort)(__float_as_uint(f1) >> 16);
                float lo0 = f0 - bf2f(h0);
                float lo1 = f1 - bf2f(h1);
                int k0 = kh * 3 + c, k1 = 9 + kh * 3 + c;
                hbuf[k0] = h0; lbuf[k0] = (ushort)(__float_as_uint(lo0) >> 16);
                hbuf[k1] = h1; lbuf[k1] = (ushort)(__float_as_uint(lo1) >> 16);
            }
        }
        // packed writes: hi at shorts [row*LSTR + qn*18, +18), lo at +72
        uint* Au = reinterpret_cast<uint*>(A);
        int hbase = (row * LSTR + qn * 18) >> 1;   // both even -> exact
        int lbase = hbase + 36;
        #pragma unroll
        for (int i = 0; i < 9; ++i) {
            Au[hbase + i] = (unsigned)hbuf[2 * i] | ((unsigned)hbuf[2 * i + 1] << 16);
            Au[lbase + i] = (unsigned)lbuf[2 * i] | ((unsigned)lbuf[2 * i + 1] << 16);
        }
        // zero K-pad shorts 144..159 (8 uints/row, 4 threads -> 2 each)
        int pbase = (row * LSTR + 144) >> 1;
        Au[pbase + qn * 2]     = 0u;
        Au[pbase + qn * 2 + 1] = 0u;
    }
    __syncthreads();

    const int lane = t & 63, wv = t >> 6;
    const int lc = lane & 15, grp = lane >> 4;
    const int no = lane & 7;
    const int par = (lane >> 3) & 1;

    // ---- GEMM: D[64 rows][256 cols], rows = px*32+ci. 5 k-steps of 32.
    f32x4 acc[4][4];
    #pragma unroll
    for (int mt = 0; mt < 4; ++mt)
        #pragma unroll
        for (int j = 0; j < 4; ++j) acc[mt][j] = (f32x4){0.f, 0.f, 0.f, 0.f};

    for (int ks = 0; ks < 5; ++ks) {
        short8 bq[4];
        #pragma unroll
        for (int j = 0; j < 4; ++j) {
            int col = wv * 64 + j * 16 + lc;
            bq[j] = *reinterpret_cast<const short8*>(wp + col * KP + ks * 32 + grp * 8);
        }
        #pragma unroll
        for (int mt = 0; mt < 4; ++mt) {
            short8 af = *reinterpret_cast<const short8*>(A + (mt * 16 + lc) * LSTR + ks * 32 + grp * 8);
            #pragma unroll
            for (int j = 0; j < 4; ++j)
                acc[mt][j] = __builtin_amdgcn_mfma_f32_16x16x32_bf16(af, bq[j], acc[mt][j], 0, 0, 0);
        }
    }
    __syncthreads();   // A dead; logits/routeT alias its LDS from here

    float bj[4];
    #pragma unroll
    for (int j = 0; j < 4; ++j) bj[j] = bias[wv * 64 + j * 16 + lc];

    const int ci_s = t >> 3, j_s = t & 7;
    float act_[2][4];

    // ================= iteration 0: route = 1/32 exactly =================
    #pragma unroll
    for (int px = 0; px < 2; ++px) {
        #pragma unroll
        for (int j = 0; j < 4; ++j) {
            const f32x4 a0 = acc[px * 2][j], a1 = acc[px * 2 + 1][j];
            float p = a0[0] + a0[1] + a0[2] + a0[3] + a1[0] + a1[1] + a1[2] + a1[3];
            p += __shfl_xor(p, 16);
            p += __shfl_xor(p, 32);             // sum over 32 ci
            p = p * 0.03125f + bj[j];
            float s2 = p * p;
            s2 += __shfl_xor(s2, 1);
            s2 += __shfl_xor(s2, 2);
            s2 += __shfl_xor(s2, 4);            // sum over no
            act_[px][j] = p * sqrtf(s2) / (1.0f + s2);
        }
    }
    // distances -> logits (pure write of all 1024 (ci,co) per pixel)
    #pragma unroll
    for (int px = 0; px < 2; ++px) {
        float* lg = px ? (fA + 2208) : fA;
        #pragma unroll
        for (int j = 0; j < 4; ++j) {
            float a = act_[px][j];
            float d[8];
            #pragma unroll
            for (int r = 0; r < 4; ++r) { d[r] = acc[px * 2][j][r] * a; d[4 + r] = acc[px * 2 + 1][j][r] * a; }
            const bool b4 = (no & 4) != 0, b2 = (no & 2) != 0, b1 = (no & 1) != 0;
            float e[4];
            #pragma unroll
            for (int k = 0; k < 4; ++k) {
                float keep = b4 ? d[k + 4] : d[k];
                float send = b4 ? d[k] : d[k + 4];
                e[k] = keep + __shfl_xor(send, 4);
            }
            float f2_[2];
            #pragma unroll
            for (int k = 0; k < 2; ++k) {
                float keep = b2 ? e[k + 2] : e[k];
                float send = b2 ? e[k] : e[k + 2];
                f2_[k] = keep + __shfl_xor(send, 2);
            }
            float keep = b1 ? f2_[1] : f2_[0];
            float send = b1 ? f2_[0] : f2_[1];
            float r = keep + __shfl_xor(send, 1);
            int ci_w = ((no >> 2) << 4) + (grp << 2) + (no & 3);
            int co   = (wv << 3) + 2 * j + par;
            lg[ci_w * 33 + co] = r;
        }
    }
    __syncthreads();

    // ================= iterations 1 and 2 =================
    for (int it = 1; it <= 2; ++it) {
        // (a) softmax over co per pixel; store transposed routeT[co][ci]
        #pragma unroll
        for (int px = 0; px < 2; ++px) {
            float* lg = px ? (fA + 2208) : fA;
            float* rt = px ? (fA + 3264) : (fA + 1056);
            float l0 = lg[ci_s * 33 + j_s];
            float l1 = lg[ci_s * 33 + j_s + 8];
            float l2 = lg[ci_s * 33 + j_s + 16];
            float l3 = lg[ci_s * 33 + j_s + 24];
            float mx = fmaxf(fmaxf(l0, l1), fmaxf(l2, l3));
            mx = fmaxf(mx, __shfl_xor(mx, 1));
            mx = fmaxf(mx, __shfl_xor(mx, 2));
            mx = fmaxf(mx, __shfl_xor(mx, 4));
            float e0 = __expf(l0 - mx), e1 = __expf(l1 - mx);
            float e2 = __expf(l2 - mx), e3 = __expf(l3 - mx);
            float s = e0 + e1 + e2 + e3;
            s += __shfl_xor(s, 1); s += __shfl_xor(s, 2); s += __shfl_xor(s, 4);
            float inv = 1.0f / s;
            rt[(j_s)      * RSTR + ci_s] = e0 * inv;
            rt[(j_s + 8)  * RSTR + ci_s] = e1 * inv;
            rt[(j_s + 16) * RSTR + ci_s] = e2 * inv;
            rt[(j_s + 24) * RSTR + ci_s] = e3 * inv;
        }
        __syncthreads();

        // (b) preactivate (ci-reduce xor16/32) + squash (no-reduce xor1/2/4)
        #pragma unroll
        for (int px = 0; px < 2; ++px) {
            float* rt = px ? (fA + 3264) : (fA + 1056);
            #pragma unroll
            for (int j = 0; j < 4; ++j) {
                int co = (wv << 3) + 2 * j + par;
                f32x4 r0 = *reinterpret_cast<const f32x4*>(rt + co * RSTR + grp * 4);
                f32x4 r1 = *reinterpret_cast<const f32x4*>(rt + co * RSTR + 16 + grp * 4);
                float p = 0.0f;
                #pragma unroll
                for (int r = 0; r < 4; ++r) p = fmaf(r0[r], acc[px * 2][j][r], p);
                #pragma unroll
                for (int r = 0; r < 4; ++r) p = fmaf(r1[r], acc[px * 2 + 1][j][r], p);
                p += __shfl_xor(p, 16);
                p += __shfl_xor(p, 32);
                p += bj[j];
                float s2 = p * p;
                s2 += __shfl_xor(s2, 1);
                s2 += __shfl_xor(s2, 2);
                s2 += __shfl_xor(s2, 4);
                act_[px][j] = p * sqrtf(s2) / (1.0f + s2);
            }
        }
        if (it == 2) break;

        // (c) distances += (butterfly), accumulate into logits
        #pragma unroll
        for (int px = 0; px < 2; ++px) {
            float* lg = px ? (fA + 2208) : fA;
            #pragma unroll
            for (int j = 0; j < 4; ++j) {
                float a = act_[px][j];
                float d[8];
                #pragma unroll
                for (int r = 0; r < 4; ++r) { d[r] = acc[px * 2][j][r] * a; d[4 + r] = acc[px * 2 + 1][j][r] * a; }
                const bool b4 = (no & 4) != 0, b2 = (no & 2) != 0, b1 = (no & 1) != 0;
                float e[4];
                #pragma unroll
                for (int k = 0; k < 4; ++k) {
                    float keep = b4 ? d[k + 4] : d[k];
                    float send = b4 ? d[k] : d[k + 4];
                    e[k] = keep + __shfl_xor(send, 4);
                }
                float f2_[2];
                #pragma unroll
                for (int k = 0; k < 2; ++k) {
                    float keep = b2 ? e[k + 2] : e[k];
                    float send = b2 ? e[k] : e[k + 2];
                    f2_[k] = keep + __shfl_xor(send, 2);
                }
                float keep = b1 ? f2_[1] : f2_[0];
                float send = b1 ? f2_[0] : f2_[1];
                float r = keep + __shfl_xor(send, 1);
                int ci_w = ((no >> 2) << 4) + (grp << 2) + (no & 3);
                int co   = (wv << 3) + 2 * j + par;
                lg[ci_w * 33 + co] += r;
            }
        }
        __syncthreads();
    }

    // ---- output: grp 0 writes the wave's 64 cols, both pixels as float2
    if (grp == 0) {
        #pragma unroll
        for (int j = 0; j < 4; ++j) {
            int col = wv * 64 + j * 16 + lc;
            float2 v; v.x = act_[0][j]; v.y = act_[1][j];
            *reinterpret_cast<float2*>(out + ((((size_t)b << 8) + col) << 10) + hw0) = v;
        }
    }
}

extern "C" void kernel_launch(void* const* d_in, const int* in_sizes, int n_in,
                              void* d_out, int out_size, void* d_ws, size_t ws_size,
                              hipStream_t stream) {
    const float* x    = (const float*)d_in[0];
    const float* cw   = (const float*)d_in[1];
    const float* bias = (const float*)d_in[2];
    float* out = (float*)d_out;
    ushort* wp = (ushort*)d_ws;           // 256*160*2 = 81,920 B
    (void)in_sizes; (void)n_in; (void)out_size; (void)ws_size;
    prep_w<<<160, 256, 0, stream>>>(cw, wp);
    caps_mfma2<<<4096, 256, 0, stream>>>(x, wp, bias, out);
}

// Round 11
// 86.721 us; speedup vs baseline: 3.3050x; 1.2485x over previous
//
#include <hip/hip_runtime.h>

// Fused capsule conv + dynamic routing: 2 pixels/block, MFMA, XCD-ownership.
// x:      [8, 32, 8, 32, 32] f32   (bs, ci, ni, hi, wi)
// conv_w: [256, 8, 3, 3]     f32   (co*no, ni, kh, kw)
// bias:   [32, 8, 1, 1]      f32
// out:    [8, 32, 8, 32, 32] f32   (bs, co, no, ho, wo)
//
// R9 (108us) minus provably-unneeded work:
//  - single-term bf16 GEMM: votes ~= rne(a)*rne(w). K=96 (3 k-steps, was 5),
//    staging halves. absmax est ~2e-3 vs 5.6e-3 threshold (R9's 9.8e-4 was
//    the dropped a*w_lo term; a_lo*w adds an independent equal term).
//  - A not aliased with routing LDS (31KB total, still >= the 4-block reg
//    cap: acc[4][4]=64 AGPR + 64 VGPR = 128/wave unified) -> post-GEMM
//    barrier dropped: 5 barriers total.
//  - softmax without max-subtract (|logits| <~ 5 << 88): -12 shfl/thread.
// Kept: pixel-pair ILP-2, shared B-frags, XCD-ownership swizzle, butterfly
// distance reduce, float2 stores, LB(256,4).

typedef __attribute__((ext_vector_type(8))) short short8;
typedef __attribute__((ext_vector_type(4))) float f32x4;

#define LSTR 104   // A row stride in ushorts (208 B; 16B-aligned, 2-way banks)
#define KP   96    // packed K per col: [hi 72][zero 24]
#define RSTR 36    // routeT row stride (f32)

__device__ __forceinline__ ushort f2bf_rne(float f) {
    unsigned u = __float_as_uint(f);
    return (ushort)((u + 0x7fffu + ((u >> 16) & 1u)) >> 16);
}

__global__ void prep_w(const float* __restrict__ cw, ushort* __restrict__ wp) {
    int e = blockIdx.x * 256 + threadIdx.x;   // [col=256][k=96]
    int col = e / KP, k = e - col * KP;
    float v = (k < 72) ? cw[col * 72 + k] : 0.0f;
    wp[e] = f2bf_rne(v);
}

__global__ __launch_bounds__(256, 4)
void caps_mfma2(const float* __restrict__ x,
                const ushort* __restrict__ wp,
                const float* __restrict__ bias,
                float* __restrict__ out)
{
    __shared__ ushort A[64 * LSTR];        // 13,312 B (not aliased)
    __shared__ float  logits[2][32 * 33];  //  8,448 B  [px][ci][co]
    __shared__ float  routeT[2][32 * RSTR];//  9,216 B  [px][co][ci]

    const int t    = threadIdx.x;
    const int braw = blockIdx.x;                 // grid = 4096
    // XCD-ownership swizzle (bijective, 4096 = 8*512): XCD k owns batch k.
    const int bid = ((braw & 7) << 9) | (braw >> 3);
    const int b   = bid >> 9;
    const int q   = bid & 511;
    const int hw0 = q << 1;                      // even; pair = (hw0, hw0+1)
    const int h   = hw0 >> 5;
    const int w0  = hw0 & 31;                    // even, <= 30

    // ---- stage A rows: thread t <-> (row = t>>2 = px*32+ci, ni in {2qn,2qn+1})
    {
        const int row = t >> 2, qn = t & 3;
        const int px = row >> 5, ci = row & 31;
        const int wpx = w0 + px;
        const float* xb0 = x + (((size_t)((b * 32 + ci) * 8 + qn * 2)) << 10);
        const float* xb1 = xb0 + 1024;
        ushort hbuf[18];
        #pragma unroll
        for (int kh = 0; kh < 3; ++kh) {
            int hy = h + kh - 1;
            bool vh = (unsigned)hy < 32u;
            int base = hy << 5;
            #pragma unroll
            for (int c = 0; c < 3; ++c) {
                int wx = wpx + c - 1;
                bool ok = vh && ((unsigned)wx < 32u);
                float f0 = ok ? xb0[base + wx] : 0.0f;
                float f1 = ok ? xb1[base + wx] : 0.0f;
                hbuf[kh * 3 + c]     = f2bf_rne(f0);
                hbuf[9 + kh * 3 + c] = f2bf_rne(f1);
            }
        }
        // packed uint writes: shorts [row*LSTR + qn*18, +18)
        uint* Au = reinterpret_cast<uint*>(A);
        int hbase = row * (LSTR / 2) + qn * 9;
        #pragma unroll
        for (int i = 0; i < 9; ++i)
            Au[hbase + i] = (unsigned)hbuf[2 * i] | ((unsigned)hbuf[2 * i + 1] << 16);
        // zero K-pad shorts 72..103 (16 uints/row, 4 threads -> 4 each)
        int pbase = row * (LSTR / 2) + 36 + qn * 4;
        Au[pbase + 0] = 0u; Au[pbase + 1] = 0u;
        Au[pbase + 2] = 0u; Au[pbase + 3] = 0u;
    }
    __syncthreads();                     // barrier 1 (staging -> GEMM)

    const int lane = t & 63, wv = t >> 6;
    const int lc = lane & 15, grp = lane >> 4;
    const int no = lane & 7;
    const int par = (lane >> 3) & 1;

    // ---- GEMM: D[64 rows][256 cols], rows = px*32+ci. 3 k-steps of 32.
    f32x4 acc[4][4];
    #pragma unroll
    for (int mt = 0; mt < 4; ++mt)
        #pragma unroll
        for (int j = 0; j < 4; ++j) acc[mt][j] = (f32x4){0.f, 0.f, 0.f, 0.f};

    #pragma unroll
    for (int ks = 0; ks < 3; ++ks) {
        short8 bq[4];
        #pragma unroll
        for (int j = 0; j < 4; ++j) {
            int col = wv * 64 + j * 16 + lc;
            bq[j] = *reinterpret_cast<const short8*>(wp + col * KP + ks * 32 + grp * 8);
        }
        #pragma unroll
        for (int mt = 0; mt < 4; ++mt) {
            short8 af = *reinterpret_cast<const short8*>(A + (mt * 16 + lc) * LSTR + ks * 32 + grp * 8);
            #pragma unroll
            for (int j = 0; j < 4; ++j)
                acc[mt][j] = __builtin_amdgcn_mfma_f32_16x16x32_bf16(af, bq[j], acc[mt][j], 0, 0, 0);
        }
    }
    // no barrier: A is read-only from here; routing uses separate buffers

    float bj[4];
    #pragma unroll
    for (int j = 0; j < 4; ++j) bj[j] = bias[wv * 64 + j * 16 + lc];

    const int ci_s = t >> 3, j_s = t & 7;
    float act_[2][4];

    // ================= iteration 0: route = 1/32 exactly =================
    #pragma unroll
    for (int px = 0; px < 2; ++px) {
        #pragma unroll
        for (int j = 0; j < 4; ++j) {
            const f32x4 a0 = acc[px * 2][j], a1 = acc[px * 2 + 1][j];
            float p = a0[0] + a0[1] + a0[2] + a0[3] + a1[0] + a1[1] + a1[2] + a1[3];
            p += __shfl_xor(p, 16);
            p += __shfl_xor(p, 32);             // sum over 32 ci
            p = p * 0.03125f + bj[j];
            float s2 = p * p;
            s2 += __shfl_xor(s2, 1);
            s2 += __shfl_xor(s2, 2);
            s2 += __shfl_xor(s2, 4);            // sum over no
            act_[px][j] = p * sqrtf(s2) / (1.0f + s2);
        }
    }
    // distances -> logits (pure write of all 1024 (ci,co) per pixel)
    #pragma unroll
    for (int px = 0; px < 2; ++px) {
        float* lg = logits[px];
        #pragma unroll
        for (int j = 0; j < 4; ++j) {
            float a = act_[px][j];
            float d[8];
            #pragma unroll
            for (int r = 0; r < 4; ++r) { d[r] = acc[px * 2][j][r] * a; d[4 + r] = acc[px * 2 + 1][j][r] * a; }
            const bool b4 = (no & 4) != 0, b2 = (no & 2) != 0, b1 = (no & 1) != 0;
            float e[4];
            #pragma unroll
            for (int k = 0; k < 4; ++k) {
                float keep = b4 ? d[k + 4] : d[k];
                float send = b4 ? d[k] : d[k + 4];
                e[k] = keep + __shfl_xor(send, 4);
            }
            float f2_[2];
            #pragma unroll
            for (int k = 0; k < 2; ++k) {
                float keep = b2 ? e[k + 2] : e[k];
                float send = b2 ? e[k] : e[k + 2];
                f2_[k] = keep + __shfl_xor(send, 2);
            }
            float keep = b1 ? f2_[1] : f2_[0];
            float send = b1 ? f2_[0] : f2_[1];
            float r = keep + __shfl_xor(send, 1);
            int ci_w = ((no >> 2) << 4) + (grp << 2) + (no & 3);
            int co   = (wv << 3) + 2 * j + par;
            lg[ci_w * 33 + co] = r;
        }
    }
    __syncthreads();                     // barrier 2 (dist0 -> softmax1)

    // ================= iterations 1 and 2 =================
    for (int it = 1; it <= 2; ++it) {
        // (a) softmax over co per pixel (no max-subtract: |logits| small);
        //     store transposed routeT[co][ci]
        #pragma unroll
        for (int px = 0; px < 2; ++px) {
            const float* lg = logits[px];
            float* rt = routeT[px];
            float e0 = __expf(lg[ci_s * 33 + j_s]);
            float e1 = __expf(lg[ci_s * 33 + j_s + 8]);
            float e2 = __expf(lg[ci_s * 33 + j_s + 16]);
            float e3 = __expf(lg[ci_s * 33 + j_s + 24]);
            float s = e0 + e1 + e2 + e3;
            s += __shfl_xor(s, 1); s += __shfl_xor(s, 2); s += __shfl_xor(s, 4);
            float inv = 1.0f / s;
            rt[(j_s)      * RSTR + ci_s] = e0 * inv;
            rt[(j_s + 8)  * RSTR + ci_s] = e1 * inv;
            rt[(j_s + 16) * RSTR + ci_s] = e2 * inv;
            rt[(j_s + 24) * RSTR + ci_s] = e3 * inv;
        }
        __syncthreads();                 // barrier 3 / 5 (routeT -> preact)

        // (b) preactivate (ci-reduce xor16/32) + squash (no-reduce xor1/2/4)
        #pragma unroll
        for (int px = 0; px < 2; ++px) {
            const float* rt = routeT[px];
            #pragma unroll
            for (int j = 0; j < 4; ++j) {
                int co = (wv << 3) + 2 * j + par;
                f32x4 r0 = *reinterpret_cast<const f32x4*>(rt + co * RSTR + grp * 4);
                f32x4 r1 = *reinterpret_cast<const f32x4*>(rt + co * RSTR + 16 + grp * 4);
                float p = 0.0f;
                #pragma unroll
                for (int r = 0; r < 4; ++r) p = fmaf(r0[r], acc[px * 2][j][r], p);
                #pragma unroll
                for (int r = 0; r < 4; ++r) p = fmaf(r1[r], acc[px * 2 + 1][j][r], p);
                p += __shfl_xor(p, 16);
                p += __shfl_xor(p, 32);
                p += bj[j];
                float s2 = p * p;
                s2 += __shfl_xor(s2, 1);
                s2 += __shfl_xor(s2, 2);
                s2 += __shfl_xor(s2, 4);
                act_[px][j] = p * sqrtf(s2) / (1.0f + s2);
            }
        }
        if (it == 2) break;

        // (c) distances += (butterfly), accumulate into logits
        #pragma unroll
        for (int px = 0; px < 2; ++px) {
            float* lg = logits[px];
            #pragma unroll
            for (int j = 0; j < 4; ++j) {
                float a = act_[px][j];
                float d[8];
                #pragma unroll
                for (int r = 0; r < 4; ++r) { d[r] = acc[px * 2][j][r] * a; d[4 + r] = acc[px * 2 + 1][j][r] * a; }
                const bool b4 = (no & 4) != 0, b2 = (no & 2) != 0, b1 = (no & 1) != 0;
                float e[4];
                #pragma unroll
                for (int k = 0; k < 4; ++k) {
                    float keep = b4 ? d[k + 4] : d[k];
                    float send = b4 ? d[k] : d[k + 4];
                    e[k] = keep + __shfl_xor(send, 4);
                }
                float f2_[2];
                #pragma unroll
                for (int k = 0; k < 2; ++k) {
                    float keep = b2 ? e[k + 2] : e[k];
                    float send = b2 ? e[k] : e[k + 2];
                    f2_[k] = keep + __shfl_xor(send, 2);
                }
                float keep = b1 ? f2_[1] : f2_[0];
                float send = b1 ? f2_[0] : f2_[1];
                float r = keep + __shfl_xor(send, 1);
                int ci_w = ((no >> 2) << 4) + (grp << 2) + (no & 3);
                int co   = (wv << 3) + 2 * j + par;
                lg[ci_w * 33 + co] += r;
            }
        }
        __syncthreads();                 // barrier 4 (dist1 -> softmax2)
    }

    // ---- output: grp 0 writes the wave's 64 cols, both pixels as float2
    if (grp == 0) {
        #pragma unroll
        for (int j = 0; j < 4; ++j) {
            int col = wv * 64 + j * 16 + lc;
            float2 v; v.x = act_[0][j]; v.y = act_[1][j];
            *reinterpret_cast<float2*>(out + ((((size_t)b << 8) + col) << 10) + hw0) = v;
        }
    }
}

extern "C" void kernel_launch(void* const* d_in, const int* in_sizes, int n_in,
                              void* d_out, int out_size, void* d_ws, size_t ws_size,
                              hipStream_t stream) {
    const float* x    = (const float*)d_in[0];
    const float* cw   = (const float*)d_in[1];
    const float* bias = (const float*)d_in[2];
    float* out = (float*)d_out;
    ushort* wp = (ushort*)d_ws;           // 256*96*2 = 49,152 B
    (void)in_sizes; (void)n_in; (void)out_size; (void)ws_size;
    prep_w<<<96, 256, 0, stream>>>(cw, wp);
    caps_mfma2<<<4096, 256, 0, stream>>>(x, wp, bias, out);
}